// Round 7
// baseline (618.601 us; speedup 1.0000x reference)
//
#include <hip/hip_runtime.h>
#include <stdint.h>
#include <math.h>

// Problem constants (fixed by reference file)
#define NROWS 32768     // B*S = 8*4096
#define DIM   256
#define KCODES 8192
#define BETA  0.25f
#define CSPLIT 4        // code splits across gemm grid.y
#define NELEM 8388608   // NROWS*DIM
// margin threshold: hi-only score error sigma ~0.003 per score (cross terms
// zhi.elo + zlo.ehi); pair sigma ~0.0045; tau = 21 sigma. Rows with
// min2-min1 < tau get exact 3-term rescore; others provably correct.
#define TAU 0.09375f

typedef float f32x4 __attribute__((ext_vector_type(4)));
typedef _Float16 v8h __attribute__((ext_vector_type(8)));
typedef unsigned short us4 __attribute__((ext_vector_type(4)));

// ---------- fp16 two-term split (Ootomo): x ~= hi + lo ----------
__device__ inline unsigned int split1(float x) {
    _Float16 hf = (_Float16)x;
    _Float16 lf = (_Float16)(x - (float)hf);
    unsigned int h = __builtin_bit_cast(unsigned short, hf);
    unsigned int l = __builtin_bit_cast(unsigned short, lf);
    return h | (l << 16);
}

__device__ inline void gload_lds16(const void* g, void* l) {
    __builtin_amdgcn_global_load_lds(
        (const __attribute__((address_space(1))) void*)g,
        (__attribute__((address_space(3))) void*)l,
        16, 0, 0);
}

// ---------- prep: z -> (z_hi, z_lo) fp16 ----------
__global__ void prep_z(const float* __restrict__ z,
                       unsigned short* __restrict__ zhi,
                       unsigned short* __restrict__ zlo) {
    int t = blockIdx.x * blockDim.x + threadIdx.x;
    float4 v = reinterpret_cast<const float4*>(z)[t];
    unsigned int p0 = split1(v.x);
    unsigned int p1 = split1(v.y);
    unsigned int p2 = split1(v.z);
    unsigned int p3 = split1(v.w);
    us4 h, l;
    h[0] = (unsigned short)p0; l[0] = (unsigned short)(p0 >> 16);
    h[1] = (unsigned short)p1; l[1] = (unsigned short)(p1 >> 16);
    h[2] = (unsigned short)p2; l[2] = (unsigned short)(p2 >> 16);
    h[3] = (unsigned short)p3; l[3] = (unsigned short)(p3 >> 16);
    reinterpret_cast<us4*>(zhi)[t] = h;
    reinterpret_cast<us4*>(zlo)[t] = l;
}

// ---------- prep: embed -> (e_hi, e_lo) fp16 + 0.5*||e||^2 fp32 ----------
__global__ void prep_e(const float* __restrict__ e,
                       unsigned short* __restrict__ ehi,
                       unsigned short* __restrict__ elo,
                       float* __restrict__ enrm) {
    int row = blockIdx.x;
    int d = threadIdx.x;
    float x = e[(size_t)row * DIM + d];
    unsigned int p = split1(x);
    ehi[(size_t)row * DIM + d] = (unsigned short)p;
    elo[(size_t)row * DIM + d] = (unsigned short)(p >> 16);
    float sq = x * x;
    #pragma unroll
    for (int off = 32; off; off >>= 1) sq += __shfl_down(sq, off);
    __shared__ float ps[4];
    if ((threadIdx.x & 63) == 0) ps[threadIdx.x >> 6] = sq;
    __syncthreads();
    if (threadIdx.x == 0) enrm[row] = 0.5f * (ps[0] + ps[1] + ps[2] + ps[3]);
}

// ---------- hi-only GEMM (K=256) + per-row (min1, argmin1, min2) ----------
// score(n,k) = 0.5||e_k||^2 - zhi_n . ehi_k  (||z||^2 row-constant, dropped)
// Structure = R4/R6 winner: BK=64, single-buffered 2-barrier K-loop, 0-conflict
// XOR swizzle (phys_group = g ^ (row&7)), 2 blocks/CU.
__launch_bounds__(256)
__global__ void gemm_hi(const unsigned short* __restrict__ zhi,
                        const unsigned short* __restrict__ ehi,
                        const float* __restrict__ enrm,
                        float* __restrict__ pval1,
                        int* __restrict__ pcol1,
                        float* __restrict__ pval2) {
    __shared__ __align__(16) unsigned short As[128 * 64];   // 16 KB
    __shared__ __align__(16) unsigned short Bs[128 * 64];   // 16 KB
    __shared__ float rv[2][128];
    __shared__ int   rc[2][128];
    __shared__ float rv2[2][128];

    const int tid = threadIdx.x;
    const int w = tid >> 6, l = tid & 63;
    const int lx = l & 15, quad = l >> 4;
    const int wm = w >> 1, wn = w & 1;
    const int arow_base = blockIdx.x * 128;
    const int cs = blockIdx.y;
    const int cbase_cs = cs * (KCODES / CSPLIT);

    float runv[16], runv2[16];
    int runc[16];
    #pragma unroll
    for (int s = 0; s < 16; ++s) {
        runv[s] = 3.0e38f; runv2[s] = 3.0e38f; runc[s] = 0x7fffffff;
    }

    const int st_row8 = l >> 3;
    const int st_g = (((l & 7) ^ (l >> 3)) * 8);
    const int fr_lx7 = lx & 7;

    for (int nt = 0; nt < (KCODES / CSPLIT) / 128; ++nt) {   // 16 N-tiles
        const int colbase = cbase_cs + nt * 128;
        f32x4 acc[4][4];
        #pragma unroll
        for (int mi = 0; mi < 4; ++mi)
            #pragma unroll
            for (int ni = 0; ni < 4; ++ni) {
                f32x4 zz = {0.f, 0.f, 0.f, 0.f};
                acc[mi][ni] = zz;
            }

        for (int bk = 0; bk < 4; ++bk) {   // K=256, BK=64
            const int ao = bk * 64;
            __syncthreads();
            #pragma unroll
            for (int j = 0; j < 4; ++j) {
                const int r = w * 32 + j * 8 + st_row8;
                gload_lds16(zhi + (size_t)(arow_base + r) * DIM + ao + st_g,
                            &As[(w * 32 + j * 8) * 64]);
                gload_lds16(ehi + (size_t)(colbase + r) * DIM + ao + st_g,
                            &Bs[(w * 32 + j * 8) * 64]);
            }
            __syncthreads();

            #pragma unroll
            for (int kc = 0; kc < 2; ++kc) {
                const int gsw = ((kc * 4 + quad) ^ fr_lx7) * 8;
                v8h af[4], bfr[4];
                #pragma unroll
                for (int mi = 0; mi < 4; ++mi)
                    af[mi] = *(const v8h*)&As[(wm * 64 + mi * 16 + lx) * 64 + gsw];
                #pragma unroll
                for (int ni = 0; ni < 4; ++ni)
                    bfr[ni] = *(const v8h*)&Bs[(wn * 64 + ni * 16 + lx) * 64 + gsw];
                #pragma unroll
                for (int mi = 0; mi < 4; ++mi)
                    #pragma unroll
                    for (int ni = 0; ni < 4; ++ni)
                        acc[mi][ni] = __builtin_amdgcn_mfma_f32_16x16x32_f16(
                            af[mi], bfr[ni], acc[mi][ni], 0, 0, 0);
            }
        }

        // epilogue: 2-min update (tie keeps earliest=lowest col; duplicate value
        // also enters min2 -> margin 0 -> row flagged -> rescue resolves).
        #pragma unroll
        for (int ni = 0; ni < 4; ++ni) {
            const int col = colbase + wn * 64 + ni * 16 + lx;
            const float es = enrm[col];
            #pragma unroll
            for (int mi = 0; mi < 4; ++mi)
                #pragma unroll
                for (int r = 0; r < 4; ++r) {
                    const int s = mi * 4 + r;
                    float sv = es - acc[mi][ni][r];
                    bool lt1 = sv < runv[s];
                    bool lt2 = sv < runv2[s];
                    float old1 = runv[s];
                    runv2[s] = lt1 ? old1 : (lt2 ? sv : runv2[s]);
                    runv[s] = lt1 ? sv : old1;
                    runc[s] = lt1 ? col : runc[s];
                }
        }
    }

    // cross-lane reduce over the 16 lx lanes (16 cols of same row per slot)
    #pragma unroll
    for (int s = 0; s < 16; ++s) {
        float v1 = runv[s], v2 = runv2[s];
        int c1 = runc[s];
        #pragma unroll
        for (int m = 1; m < 16; m <<= 1) {
            float ov1 = __shfl_xor(v1, m);
            int oc1 = __shfl_xor(c1, m);
            float ov2 = __shfl_xor(v2, m);
            float mx = fmaxf(v1, ov1);
            v2 = fminf(fminf(v2, ov2), mx);
            bool take = (ov1 < v1) || (ov1 == v1 && oc1 < c1);
            v1 = take ? ov1 : v1;
            c1 = take ? oc1 : c1;
        }
        if (lx == 0) {
            const int mi = s >> 2, r = s & 3;
            const int rl = wm * 64 + mi * 16 + quad * 4 + r;
            rv[wn][rl] = v1; rc[wn][rl] = c1; rv2[wn][rl] = v2;
        }
    }
    __syncthreads();
    if (tid < 128) {
        float v1 = rv[0][tid], v2 = rv2[0][tid];
        int c1 = rc[0][tid];
        float ov1 = rv[1][tid], ov2 = rv2[1][tid];
        int oc1 = rc[1][tid];
        float mx = fmaxf(v1, ov1);
        v2 = fminf(fminf(v2, ov2), mx);
        bool take = (ov1 < v1) || (ov1 == v1 && oc1 < c1);
        v1 = take ? ov1 : v1;
        c1 = take ? oc1 : c1;
        const size_t row = (size_t)arow_base + tid;
        pval1[row * CSPLIT + cs] = v1;
        pcol1[row * CSPLIT + cs] = c1;
        pval2[row * CSPLIT + cs] = v2;
    }
}

// ---------- merge splits, write tentative idx, flag low-margin rows ----------
__global__ void merge_flag(const float* __restrict__ pval1,
                           const int* __restrict__ pcol1,
                           const float* __restrict__ pval2,
                           int* __restrict__ colidx,
                           float* __restrict__ out_idx,
                           int* __restrict__ flagcnt,
                           int* __restrict__ flaglist) {
    int row = blockIdx.x * blockDim.x + threadIdx.x;
    float v1 = pval1[row * CSPLIT], v2 = pval2[row * CSPLIT];
    int c1 = pcol1[row * CSPLIT];
    #pragma unroll
    for (int cs = 1; cs < CSPLIT; ++cs) {
        float ov1 = pval1[row * CSPLIT + cs], ov2 = pval2[row * CSPLIT + cs];
        int oc1 = pcol1[row * CSPLIT + cs];
        float mx = fmaxf(v1, ov1);
        v2 = fminf(fminf(v2, ov2), mx);
        if (ov1 < v1 || (ov1 == v1 && oc1 < c1)) { v1 = ov1; c1 = oc1; }
    }
    colidx[row] = c1;
    out_idx[row] = (float)c1;
    if (v2 - v1 < TAU) {
        int slot = atomicAdd(flagcnt, 1);
        flaglist[slot] = row;   // cap 32768 = NROWS, cannot overflow
    }
}

// ---------- rescue: exact 3-term split GEMM over flagged rows only ----------
// A' = [zhi|zhi|zlo], B' = [ehi|elo|ehi] (K=768) -- same arithmetic that scored
// absmax=0 full-problem in R2/R4/R6. Fixed grid (16,CSPLIT), device-count
// stride loop; pad rows -> row 0 (harmless: unflagged rows' 3-term argmin
// equals their hi argmin by the margin bound; writes are guarded anyway).
__launch_bounds__(256)
__global__ void rescue_gemm(const unsigned short* __restrict__ zhi,
                            const unsigned short* __restrict__ zlo,
                            const unsigned short* __restrict__ ehi,
                            const unsigned short* __restrict__ elo,
                            const float* __restrict__ enrm,
                            const int* __restrict__ flagcnt,
                            const int* __restrict__ flaglist,
                            float* __restrict__ pval,
                            int* __restrict__ pcol) {
    __shared__ __align__(16) unsigned short As[128 * 64];
    __shared__ __align__(16) unsigned short Bs[128 * 64];
    __shared__ float rv[2][128];
    __shared__ int   rc[2][128];

    const int count = *flagcnt;
    const int tid = threadIdx.x;
    const int w = tid >> 6, l = tid & 63;
    const int lx = l & 15, quad = l >> 4;
    const int wm = w >> 1, wn = w & 1;
    const int cs = blockIdx.y;
    const int cbase_cs = cs * (KCODES / CSPLIT);

    const int st_row8 = l >> 3;
    const int st_g = (((l & 7) ^ (l >> 3)) * 8);
    const int fr_lx7 = lx & 7;

    for (int tb = blockIdx.x * 128; tb < count; tb += 16 * 128) {
        // per-lane A-source rows (indirect through flaglist)
        int arowj[4];
        #pragma unroll
        for (int j = 0; j < 4; ++j) {
            int li = tb + w * 32 + j * 8 + st_row8;
            arowj[j] = (li < count) ? flaglist[li] : 0;
        }

        float runv[16];
        int runc[16];
        #pragma unroll
        for (int s = 0; s < 16; ++s) { runv[s] = 3.0e38f; runc[s] = 0x7fffffff; }

        for (int nt = 0; nt < (KCODES / CSPLIT) / 128; ++nt) {
            const int colbase = cbase_cs + nt * 128;
            f32x4 acc[4][4];
            #pragma unroll
            for (int mi = 0; mi < 4; ++mi)
                #pragma unroll
                for (int ni = 0; ni < 4; ++ni) {
                    f32x4 zz = {0.f, 0.f, 0.f, 0.f};
                    acc[mi][ni] = zz;
                }

            #pragma unroll
            for (int seg = 0; seg < 3; ++seg) {
                const unsigned short* za = (seg == 2) ? zlo : zhi;
                const unsigned short* eb = (seg == 1) ? elo : ehi;
                for (int bk = 0; bk < 4; ++bk) {
                    const int ao = bk * 64;
                    __syncthreads();
                    #pragma unroll
                    for (int j = 0; j < 4; ++j) {
                        const int r = w * 32 + j * 8 + st_row8;
                        gload_lds16(za + (size_t)arowj[j] * DIM + ao + st_g,
                                    &As[(w * 32 + j * 8) * 64]);
                        gload_lds16(eb + (size_t)(colbase + r) * DIM + ao + st_g,
                                    &Bs[(w * 32 + j * 8) * 64]);
                    }
                    __syncthreads();
                    #pragma unroll
                    for (int kc = 0; kc < 2; ++kc) {
                        const int gsw = ((kc * 4 + quad) ^ fr_lx7) * 8;
                        v8h af[4], bfr[4];
                        #pragma unroll
                        for (int mi = 0; mi < 4; ++mi)
                            af[mi] = *(const v8h*)&As[(wm * 64 + mi * 16 + lx) * 64 + gsw];
                        #pragma unroll
                        for (int ni = 0; ni < 4; ++ni)
                            bfr[ni] = *(const v8h*)&Bs[(wn * 64 + ni * 16 + lx) * 64 + gsw];
                        #pragma unroll
                        for (int mi = 0; mi < 4; ++mi)
                            #pragma unroll
                            for (int ni = 0; ni < 4; ++ni)
                                acc[mi][ni] = __builtin_amdgcn_mfma_f32_16x16x32_f16(
                                    af[mi], bfr[ni], acc[mi][ni], 0, 0, 0);
                    }
                }
            }

            #pragma unroll
            for (int ni = 0; ni < 4; ++ni) {
                const int col = colbase + wn * 64 + ni * 16 + lx;
                const float es = enrm[col];
                #pragma unroll
                for (int mi = 0; mi < 4; ++mi)
                    #pragma unroll
                    for (int r = 0; r < 4; ++r) {
                        float sv = es - acc[mi][ni][r];
                        const int s = mi * 4 + r;
                        if (sv < runv[s]) { runv[s] = sv; runc[s] = col; }
                    }
            }
        }

        #pragma unroll
        for (int s = 0; s < 16; ++s) {
            float v = runv[s]; int c = runc[s];
            #pragma unroll
            for (int m = 1; m < 16; m <<= 1) {
                float ov = __shfl_xor(v, m);
                int oc = __shfl_xor(c, m);
                if (ov < v || (ov == v && oc < c)) { v = ov; c = oc; }
            }
            if (lx == 0) {
                const int mi = s >> 2, r = s & 3;
                const int rl = wm * 64 + mi * 16 + quad * 4 + r;
                rv[wn][rl] = v; rc[wn][rl] = c;
            }
        }
        __syncthreads();
        if (tid < 128) {
            float v0 = rv[0][tid]; int c0 = rc[0][tid];
            float v1 = rv[1][tid]; int c1 = rc[1][tid];
            if (v1 < v0 || (v1 == v0 && c1 < c0)) { v0 = v1; c0 = c1; }
            const int li = tb + tid;
            if (li < count) {
                pval[li * CSPLIT + cs] = v0;
                pcol[li * CSPLIT + cs] = c0;
            }
        }
        __syncthreads();
    }
}

// ---------- merge rescue partials, overwrite idx for flagged rows ----------
__global__ void merge_rescue(const float* __restrict__ pval,
                             const int* __restrict__ pcol,
                             const int* __restrict__ flagcnt,
                             const int* __restrict__ flaglist,
                             int* __restrict__ colidx,
                             float* __restrict__ out_idx) {
    int i = blockIdx.x * blockDim.x + threadIdx.x;
    if (i >= *flagcnt) return;
    int row = flaglist[i];
    float bv = pval[i * CSPLIT]; int bc = pcol[i * CSPLIT];
    #pragma unroll
    for (int cs = 1; cs < CSPLIT; ++cs) {
        float v = pval[i * CSPLIT + cs]; int c = pcol[i * CSPLIT + cs];
        if (v < bv || (v == bv && c < bc)) { bv = v; bc = c; }
    }
    colidx[row] = bc;
    out_idx[row] = (float)bc;
}

// ---------- gather z_q, z_q_st, loss, histogram ----------
__global__ void fused_out(const int* __restrict__ colidx,
                          const float* __restrict__ z,
                          const float* __restrict__ embed,
                          float* __restrict__ out_zq,
                          float* __restrict__ counts,
                          float* __restrict__ lossAcc) {
    __shared__ int cidx[16];
    const int tid = threadIdx.x;
    if (tid < 16) {
        const int row = blockIdx.x * 16 + tid;
        const int c = colidx[row];
        cidx[tid] = c;
        atomicAdd(&counts[c], 1.0f);
    }
    __syncthreads();
    const int d = tid;
    float ls = 0.f;
    #pragma unroll 4
    for (int i = 0; i < 16; ++i) {
        const int row = blockIdx.x * 16 + i;
        const int c = cidx[i];
        const float zv = z[(size_t)row * DIM + d];
        const float ev = embed[(size_t)c * DIM + d];
        const float diff = ev - zv;
        out_zq[(size_t)row * DIM + d] = zv + diff;
        ls += diff * diff;
    }
    #pragma unroll
    for (int off = 32; off; off >>= 1) ls += __shfl_down(ls, off);
    __shared__ float ps[4];
    if ((tid & 63) == 0) ps[tid >> 6] = ls;
    __syncthreads();
    if (tid == 0) atomicAdd(lossAcc, ps[0] + ps[1] + ps[2] + ps[3]);
}

// ---------- loss scale + perplexity ----------
__global__ void finalize(const float* __restrict__ counts,
                         const float* __restrict__ lossAcc,
                         float* __restrict__ out_loss,
                         float* __restrict__ out_perp) {
    float h = 0.f;
    for (int k = threadIdx.x; k < KCODES; k += 256) {
        float p = counts[k] * (1.0f / (float)NROWS);
        h += p * logf(p + 1e-12f);
    }
    #pragma unroll
    for (int off = 32; off; off >>= 1) h += __shfl_down(h, off);
    __shared__ float ps[4];
    if ((threadIdx.x & 63) == 0) ps[threadIdx.x >> 6] = h;
    __syncthreads();
    if (threadIdx.x == 0) {
        *out_perp = expf(-(ps[0] + ps[1] + ps[2] + ps[3]));
        *out_loss = BETA * lossAcc[0] / (float)NELEM;
    }
}

extern "C" void kernel_launch(void* const* d_in, const int* in_sizes, int n_in,
                              void* d_out, int out_size, void* d_ws, size_t ws_size,
                              hipStream_t stream) {
    const float* z = (const float*)d_in[0];       // [32768, 256] f32
    const float* embed = (const float*)d_in[1];   // [8192, 256] f32
    char* ws = (char*)d_ws;

    // workspace layout (~43.9 MB)
    unsigned short* zhi = (unsigned short*)(ws + 0);           // 16 MB
    unsigned short* zlo = (unsigned short*)(ws + 16777216);    // 16 MB
    unsigned short* ehi = (unsigned short*)(ws + 33554432);    // 4 MB
    unsigned short* elo = (unsigned short*)(ws + 37748736);    // 4 MB
    float* enrm    = (float*)(ws + 41943040);                  // 32 KB
    float* pval1   = (float*)(ws + 41975808);                  // 512 KB
    int*   pcol1   = (int*)  (ws + 42500096);                  // 512 KB
    float* pval2   = (float*)(ws + 43024384);                  // 512 KB
    int*   colidx  = (int*)  (ws + 43548672);                  // 128 KB
    float* counts  = (float*)(ws + 43679744);                  // 32 KB
    float* lossAcc = (float*)(ws + 43712512);                  // 4 B
    int*   flagcnt = (int*)  (ws + 43712516);                  // 4 B
    int*   flaglist = (int*) (ws + 43712520);                  // 128 KB -> ends ~43.84 MB

    float* out = (float*)d_out;
    float* out_zq   = out;                 // 8388608
    float* out_loss = out + 8388608;       // 1
    float* out_perp = out + 8388609;       // 1
    float* out_idx  = out + 8388610;       // 32768 (indices as f32)

    // zero histogram + loss accumulator + flag counter (contiguous)
    (void)hipMemsetAsync(counts, 0, KCODES * 4 + 8, stream);

    prep_z<<<NELEM / 4 / 256, 256, 0, stream>>>(z, zhi, zlo);
    prep_e<<<KCODES, 256, 0, stream>>>(embed, ehi, elo, enrm);
    gemm_hi<<<dim3(NROWS / 128, CSPLIT), 256, 0, stream>>>(
        zhi, ehi, enrm, pval1, pcol1, pval2);
    merge_flag<<<NROWS / 256, 256, 0, stream>>>(
        pval1, pcol1, pval2, colidx, out_idx, flagcnt, flaglist);
    rescue_gemm<<<dim3(16, CSPLIT), 256, 0, stream>>>(
        zhi, zlo, ehi, elo, enrm, flagcnt, flaglist, pval1, pcol1);
    merge_rescue<<<NROWS / 256, 256, 0, stream>>>(
        pval1, pcol1, flagcnt, flaglist, colidx, out_idx);
    fused_out<<<NROWS / 16, 256, 0, stream>>>(colidx, z, embed,
                                              out_zq, counts, lossAcc);
    finalize<<<1, 256, 0, stream>>>(counts, lossAcc, out_loss, out_perp);
}

// Round 8
// 597.156 us; speedup vs baseline: 1.0359x; 1.0359x over previous
//
#include <hip/hip_runtime.h>
#include <stdint.h>
#include <math.h>

// Problem constants (fixed by reference file)
#define NROWS 32768     // B*S = 8*4096
#define DIM   256
#define KCODES 8192
#define BETA  0.25f
#define CSPLIT 4        // code splits across gemm grid.y (also rescue col-splits)
#define NELEM 8388608   // NROWS*DIM
// margin threshold: hi-only score error sigma ~6e-3 per score (cross terms
// zhi.elo + zlo.ehi); pair sigma ~9e-3; tau ~ 10 sigma. Rows with
// min2-min1 < tau get exact fp32 rescore; others safe with overwhelming prob.
#define TAU 0.09375f

typedef float f32x4 __attribute__((ext_vector_type(4)));
typedef _Float16 v8h __attribute__((ext_vector_type(8)));
typedef unsigned short us4 __attribute__((ext_vector_type(4)));

// ---------- fp16 two-term split (Ootomo): x ~= hi + lo ----------
__device__ inline unsigned int split1(float x) {
    _Float16 hf = (_Float16)x;
    _Float16 lf = (_Float16)(x - (float)hf);
    unsigned int h = __builtin_bit_cast(unsigned short, hf);
    unsigned int l = __builtin_bit_cast(unsigned short, lf);
    return h | (l << 16);
}

__device__ inline void gload_lds16(const void* g, void* l) {
    __builtin_amdgcn_global_load_lds(
        (const __attribute__((address_space(1))) void*)g,
        (__attribute__((address_space(3))) void*)l,
        16, 0, 0);
}

// ---------- prep: z -> (z_hi) fp16 (zlo not needed: rescue uses fp32 z) ----------
__global__ void prep_z(const float* __restrict__ z,
                       unsigned short* __restrict__ zhi) {
    int t = blockIdx.x * blockDim.x + threadIdx.x;
    float4 v = reinterpret_cast<const float4*>(z)[t];
    us4 h;
    h[0] = (unsigned short)split1(v.x);
    h[1] = (unsigned short)split1(v.y);
    h[2] = (unsigned short)split1(v.z);
    h[3] = (unsigned short)split1(v.w);
    reinterpret_cast<us4*>(zhi)[t] = h;
}

// ---------- prep: embed -> e_hi fp16 + 0.5*||e||^2 fp32 ----------
__global__ void prep_e(const float* __restrict__ e,
                       unsigned short* __restrict__ ehi,
                       float* __restrict__ enrm) {
    int row = blockIdx.x;
    int d = threadIdx.x;
    float x = e[(size_t)row * DIM + d];
    ehi[(size_t)row * DIM + d] = (unsigned short)split1(x);
    float sq = x * x;
    #pragma unroll
    for (int off = 32; off; off >>= 1) sq += __shfl_down(sq, off);
    __shared__ float ps[4];
    if ((threadIdx.x & 63) == 0) ps[threadIdx.x >> 6] = sq;
    __syncthreads();
    if (threadIdx.x == 0) enrm[row] = 0.5f * (ps[0] + ps[1] + ps[2] + ps[3]);
}

// ---------- hi-only GEMM (K=256) + per-row (min1, argmin1, min2) ----------
// score(n,k) = 0.5||e_k||^2 - zhi_n . ehi_k  (||z||^2 row-constant, dropped)
// Structure = R4/R6 winner: BK=64, single-buffered 2-barrier K-loop, 0-conflict
// XOR swizzle. __launch_bounds__(256,2): R7 post-mortem -- without the min-waves
// bound the compiler allocated >256 regs/wave -> 1 block/CU -> MfmaUtil 17%.
// Kernel needs ~210 regs; forcing <=256 restores 2 blocks/CU.
__launch_bounds__(256, 2)
__global__ void gemm_hi(const unsigned short* __restrict__ zhi,
                        const unsigned short* __restrict__ ehi,
                        const float* __restrict__ enrm,
                        float* __restrict__ pval1,
                        int* __restrict__ pcol1,
                        float* __restrict__ pval2) {
    __shared__ __align__(16) unsigned short As[128 * 64];   // 16 KB
    __shared__ __align__(16) unsigned short Bs[128 * 64];   // 16 KB
    __shared__ float rv[2][128];
    __shared__ int   rc[2][128];
    __shared__ float rv2[2][128];

    const int tid = threadIdx.x;
    const int w = tid >> 6, l = tid & 63;
    const int lx = l & 15, quad = l >> 4;
    const int wm = w >> 1, wn = w & 1;
    const int arow_base = blockIdx.x * 128;
    const int cs = blockIdx.y;
    const int cbase_cs = cs * (KCODES / CSPLIT);

    float runv[16], runv2[16];
    int runc[16];
    #pragma unroll
    for (int s = 0; s < 16; ++s) {
        runv[s] = 3.0e38f; runv2[s] = 3.0e38f; runc[s] = 0x7fffffff;
    }

    const int st_row8 = l >> 3;
    const int st_g = (((l & 7) ^ (l >> 3)) * 8);
    const int fr_lx7 = lx & 7;

    for (int nt = 0; nt < (KCODES / CSPLIT) / 128; ++nt) {   // 16 N-tiles
        const int colbase = cbase_cs + nt * 128;
        f32x4 acc[4][4];
        #pragma unroll
        for (int mi = 0; mi < 4; ++mi)
            #pragma unroll
            for (int ni = 0; ni < 4; ++ni) {
                f32x4 zz = {0.f, 0.f, 0.f, 0.f};
                acc[mi][ni] = zz;
            }

        for (int bk = 0; bk < 4; ++bk) {   // K=256, BK=64
            const int ao = bk * 64;
            __syncthreads();
            #pragma unroll
            for (int j = 0; j < 4; ++j) {
                const int r = w * 32 + j * 8 + st_row8;
                gload_lds16(zhi + (size_t)(arow_base + r) * DIM + ao + st_g,
                            &As[(w * 32 + j * 8) * 64]);
                gload_lds16(ehi + (size_t)(colbase + r) * DIM + ao + st_g,
                            &Bs[(w * 32 + j * 8) * 64]);
            }
            __syncthreads();

            #pragma unroll
            for (int kc = 0; kc < 2; ++kc) {
                const int gsw = ((kc * 4 + quad) ^ fr_lx7) * 8;
                v8h af[4], bfr[4];
                #pragma unroll
                for (int mi = 0; mi < 4; ++mi)
                    af[mi] = *(const v8h*)&As[(wm * 64 + mi * 16 + lx) * 64 + gsw];
                #pragma unroll
                for (int ni = 0; ni < 4; ++ni)
                    bfr[ni] = *(const v8h*)&Bs[(wn * 64 + ni * 16 + lx) * 64 + gsw];
                #pragma unroll
                for (int mi = 0; mi < 4; ++mi)
                    #pragma unroll
                    for (int ni = 0; ni < 4; ++ni)
                        acc[mi][ni] = __builtin_amdgcn_mfma_f32_16x16x32_f16(
                            af[mi], bfr[ni], acc[mi][ni], 0, 0, 0);
            }
        }

        // epilogue: 2-min update (tie -> margin 0 -> flagged -> rescue resolves)
        #pragma unroll
        for (int ni = 0; ni < 4; ++ni) {
            const int col = colbase + wn * 64 + ni * 16 + lx;
            const float es = enrm[col];
            #pragma unroll
            for (int mi = 0; mi < 4; ++mi)
                #pragma unroll
                for (int r = 0; r < 4; ++r) {
                    const int s = mi * 4 + r;
                    float sv = es - acc[mi][ni][r];
                    bool lt1 = sv < runv[s];
                    bool lt2 = sv < runv2[s];
                    float old1 = runv[s];
                    runv2[s] = lt1 ? old1 : (lt2 ? sv : runv2[s]);
                    runv[s] = lt1 ? sv : old1;
                    runc[s] = lt1 ? col : runc[s];
                }
        }
    }

    // cross-lane reduce over the 16 lx lanes (16 cols of same row per slot)
    #pragma unroll
    for (int s = 0; s < 16; ++s) {
        float v1 = runv[s], v2 = runv2[s];
        int c1 = runc[s];
        #pragma unroll
        for (int m = 1; m < 16; m <<= 1) {
            float ov1 = __shfl_xor(v1, m);
            int oc1 = __shfl_xor(c1, m);
            float ov2 = __shfl_xor(v2, m);
            float mx = fmaxf(v1, ov1);
            v2 = fminf(fminf(v2, ov2), mx);
            bool take = (ov1 < v1) || (ov1 == v1 && oc1 < c1);
            v1 = take ? ov1 : v1;
            c1 = take ? oc1 : c1;
        }
        if (lx == 0) {
            const int mi = s >> 2, r = s & 3;
            const int rl = wm * 64 + mi * 16 + quad * 4 + r;
            rv[wn][rl] = v1; rc[wn][rl] = c1; rv2[wn][rl] = v2;
        }
    }
    __syncthreads();
    if (tid < 128) {
        float v1 = rv[0][tid], v2 = rv2[0][tid];
        int c1 = rc[0][tid];
        float ov1 = rv[1][tid], ov2 = rv2[1][tid];
        int oc1 = rc[1][tid];
        float mx = fmaxf(v1, ov1);
        v2 = fminf(fminf(v2, ov2), mx);
        bool take = (ov1 < v1) || (ov1 == v1 && oc1 < c1);
        v1 = take ? ov1 : v1;
        c1 = take ? oc1 : c1;
        const size_t row = (size_t)arow_base + tid;
        pval1[row * CSPLIT + cs] = v1;
        pcol1[row * CSPLIT + cs] = c1;
        pval2[row * CSPLIT + cs] = v2;
    }
}

// ---------- merge splits, write tentative idx, flag low-margin rows ----------
__global__ void merge_flag(const float* __restrict__ pval1,
                           const int* __restrict__ pcol1,
                           const float* __restrict__ pval2,
                           int* __restrict__ colidx,
                           float* __restrict__ out_idx,
                           int* __restrict__ flagcnt,
                           int* __restrict__ flaglist) {
    int row = blockIdx.x * blockDim.x + threadIdx.x;
    float v1 = pval1[row * CSPLIT], v2 = pval2[row * CSPLIT];
    int c1 = pcol1[row * CSPLIT];
    #pragma unroll
    for (int cs = 1; cs < CSPLIT; ++cs) {
        float ov1 = pval1[row * CSPLIT + cs], ov2 = pval2[row * CSPLIT + cs];
        int oc1 = pcol1[row * CSPLIT + cs];
        float mx = fmaxf(v1, ov1);
        v2 = fminf(fminf(v2, ov2), mx);
        if (ov1 < v1 || (ov1 == v1 && oc1 < c1)) { v1 = ov1; c1 = oc1; }
    }
    colidx[row] = c1;
    out_idx[row] = (float)c1;
    if (v2 - v1 < TAU) {
        int slot = atomicAdd(flagcnt, 1);
        flaglist[slot] = row;   // cap 32768 = NROWS, cannot overflow
    }
}

// ---------- rescue: exact fp32 rescore of flagged rows (VALU, full 8192 cols) ----
// grid (64, CSPLIT), block 256. Each block: 8 flagged rows x 2048 cols.
// z-rows in LDS (broadcast reads); embed streamed (L1 reuses 64B lines 4x).
// score = 0.5||e||^2 - z.e in fp32 -- error ~1e-5, far below flagged-row
// ambiguity except for ties the reference itself resolves by order.
__launch_bounds__(256)
__global__ void rescue_scan(const float* __restrict__ z,
                            const float* __restrict__ embed,
                            const float* __restrict__ enrm,
                            const int* __restrict__ flagcnt,
                            const int* __restrict__ flaglist,
                            float* __restrict__ rval,
                            int* __restrict__ rcol) {
    const int count = *flagcnt;
    const int split = blockIdx.y;
    const int colbase = split * (KCODES / CSPLIT);   // 2048 cols per split
    const int tid = threadIdx.x;
    __shared__ float zs[8][DIM];     // 8 KB
    __shared__ float wvs[8][4];
    __shared__ int   wcs[8][4];

    for (int rb = blockIdx.x * 8; rb < count; rb += 64 * 8) {
        __syncthreads();   // protect zs from previous iteration's readers
        #pragma unroll
        for (int i = 0; i < 2; ++i) {
            int idx = tid + i * 256;          // float4 index 0..511
            int r = idx >> 6;                 // 64 float4 per row
            int li = rb + r;
            int zrow = flaglist[li < count ? li : count - 1];
            reinterpret_cast<float4*>(&zs[r][0])[idx & 63] =
                reinterpret_cast<const float4*>(z + (size_t)zrow * DIM)[idx & 63];
        }
        __syncthreads();

        float best[8]; int bcol[8];
        #pragma unroll
        for (int r = 0; r < 8; ++r) { best[r] = 3.0e38f; bcol[r] = 0x7fffffff; }

        for (int cc = 0; cc < KCODES / CSPLIT; cc += 256) {
            const int col = colbase + cc + tid;
            const float4* ep = reinterpret_cast<const float4*>(embed + (size_t)col * DIM);
            float acc[8];
            #pragma unroll
            for (int r = 0; r < 8; ++r) acc[r] = 0.f;
            for (int d4 = 0; d4 < 64; ++d4) {
                float4 ev = ep[d4];
                float4 zr;
                #pragma unroll
                for (int r = 0; r < 8; ++r) {
                    zr = *reinterpret_cast<const float4*>(&zs[r][d4 * 4]);
                    acc[r] += zr.x * ev.x + zr.y * ev.y + zr.z * ev.z + zr.w * ev.w;
                }
            }
            const float es = enrm[col];
            #pragma unroll
            for (int r = 0; r < 8; ++r) {
                float sv = es - acc[r];
                if (sv < best[r]) { best[r] = sv; bcol[r] = col; }
            }
        }

        // reduce across 256 threads per row
        const int w = tid >> 6, l = tid & 63;
        #pragma unroll
        for (int r = 0; r < 8; ++r) {
            float v = best[r]; int c = bcol[r];
            #pragma unroll
            for (int m = 1; m < 64; m <<= 1) {
                float ov = __shfl_xor(v, m);
                int oc = __shfl_xor(c, m);
                if (ov < v || (ov == v && oc < c)) { v = ov; c = oc; }
            }
            if (l == 0) { wvs[r][w] = v; wcs[r][w] = c; }
        }
        __syncthreads();
        if (tid < 8) {
            float v = wvs[tid][0]; int c = wcs[tid][0];
            #pragma unroll
            for (int i = 1; i < 4; ++i) {
                float ov = wvs[tid][i]; int oc = wcs[tid][i];
                if (ov < v || (ov == v && oc < c)) { v = ov; c = oc; }
            }
            const int li = rb + tid;
            if (li < count) {
                rval[li * CSPLIT + split] = v;
                rcol[li * CSPLIT + split] = c;
            }
        }
    }
}

// ---------- merge rescue partials, overwrite idx for flagged rows ----------
__global__ void merge_rescue(const float* __restrict__ rval,
                             const int* __restrict__ rcol,
                             const int* __restrict__ flagcnt,
                             const int* __restrict__ flaglist,
                             int* __restrict__ colidx,
                             float* __restrict__ out_idx) {
    int i = blockIdx.x * blockDim.x + threadIdx.x;
    if (i >= *flagcnt) return;
    int row = flaglist[i];
    float bv = rval[i * CSPLIT]; int bc = rcol[i * CSPLIT];
    #pragma unroll
    for (int cs = 1; cs < CSPLIT; ++cs) {
        float v = rval[i * CSPLIT + cs]; int c = rcol[i * CSPLIT + cs];
        if (v < bv || (v == bv && c < bc)) { bv = v; bc = c; }
    }
    colidx[row] = bc;
    out_idx[row] = (float)bc;
}

// ---------- gather z_q, z_q_st, loss, histogram ----------
__global__ void fused_out(const int* __restrict__ colidx,
                          const float* __restrict__ z,
                          const float* __restrict__ embed,
                          float* __restrict__ out_zq,
                          float* __restrict__ counts,
                          float* __restrict__ lossAcc) {
    __shared__ int cidx[16];
    const int tid = threadIdx.x;
    if (tid < 16) {
        const int row = blockIdx.x * 16 + tid;
        const int c = colidx[row];
        cidx[tid] = c;
        atomicAdd(&counts[c], 1.0f);
    }
    __syncthreads();
    const int d = tid;
    float ls = 0.f;
    #pragma unroll 4
    for (int i = 0; i < 16; ++i) {
        const int row = blockIdx.x * 16 + i;
        const int c = cidx[i];
        const float zv = z[(size_t)row * DIM + d];
        const float ev = embed[(size_t)c * DIM + d];
        const float diff = ev - zv;
        out_zq[(size_t)row * DIM + d] = zv + diff;
        ls += diff * diff;
    }
    #pragma unroll
    for (int off = 32; off; off >>= 1) ls += __shfl_down(ls, off);
    __shared__ float ps[4];
    if ((tid & 63) == 0) ps[tid >> 6] = ls;
    __syncthreads();
    if (tid == 0) atomicAdd(lossAcc, ps[0] + ps[1] + ps[2] + ps[3]);
}

// ---------- loss scale + perplexity ----------
__global__ void finalize(const float* __restrict__ counts,
                         const float* __restrict__ lossAcc,
                         float* __restrict__ out_loss,
                         float* __restrict__ out_perp) {
    float h = 0.f;
    for (int k = threadIdx.x; k < KCODES; k += 256) {
        float p = counts[k] * (1.0f / (float)NROWS);
        h += p * logf(p + 1e-12f);
    }
    #pragma unroll
    for (int off = 32; off; off >>= 1) h += __shfl_down(h, off);
    __shared__ float ps[4];
    if ((threadIdx.x & 63) == 0) ps[threadIdx.x >> 6] = h;
    __syncthreads();
    if (threadIdx.x == 0) {
        *out_perp = expf(-(ps[0] + ps[1] + ps[2] + ps[3]));
        *out_loss = BETA * lossAcc[0] / (float)NELEM;
    }
}

extern "C" void kernel_launch(void* const* d_in, const int* in_sizes, int n_in,
                              void* d_out, int out_size, void* d_ws, size_t ws_size,
                              hipStream_t stream) {
    const float* z = (const float*)d_in[0];       // [32768, 256] f32
    const float* embed = (const float*)d_in[1];   // [8192, 256] f32
    char* ws = (char*)d_ws;

    // workspace layout (~22.5 MB; zlo/elo no longer needed)
    unsigned short* zhi = (unsigned short*)(ws + 0);           // 16 MB
    unsigned short* ehi = (unsigned short*)(ws + 16777216);    // 4 MB
    float* enrm    = (float*)(ws + 20971520);                  // 32 KB
    float* pval1   = (float*)(ws + 21004288);                  // 512 KB
    int*   pcol1   = (int*)  (ws + 21528576);                  // 512 KB
    float* pval2   = (float*)(ws + 22052864);                  // 512 KB
    int*   colidx  = (int*)  (ws + 22577152);                  // 128 KB
    float* counts  = (float*)(ws + 22708224);                  // 32 KB
    float* lossAcc = (float*)(ws + 22740992);                  // 4 B
    int*   flagcnt = (int*)  (ws + 22740996);                  // 4 B
    int*   flaglist = (int*) (ws + 22741000);                  // 128 KB

    // rescue partials reuse pval1/pcol1 (dead after merge_flag)
    float* rval = pval1;
    int*   rcol = pcol1;

    float* out = (float*)d_out;
    float* out_zq   = out;                 // 8388608
    float* out_loss = out + 8388608;       // 1
    float* out_perp = out + 8388609;       // 1
    float* out_idx  = out + 8388610;       // 32768 (indices as f32)

    // zero histogram + loss accumulator + flag counter (contiguous)
    (void)hipMemsetAsync(counts, 0, KCODES * 4 + 8, stream);

    prep_z<<<NELEM / 4 / 256, 256, 0, stream>>>(z, zhi);
    prep_e<<<KCODES, 256, 0, stream>>>(embed, ehi, enrm);
    gemm_hi<<<dim3(NROWS / 128, CSPLIT), 256, 0, stream>>>(
        zhi, ehi, enrm, pval1, pcol1, pval2);
    merge_flag<<<NROWS / 256, 256, 0, stream>>>(
        pval1, pcol1, pval2, colidx, out_idx, flagcnt, flaglist);
    rescue_scan<<<dim3(64, CSPLIT), 256, 0, stream>>>(
        z, embed, enrm, flagcnt, flaglist, rval, rcol);
    merge_rescue<<<NROWS / 256, 256, 0, stream>>>(
        rval, rcol, flagcnt, flaglist, colidx, out_idx);
    fused_out<<<NROWS / 16, 256, 0, stream>>>(colidx, z, embed,
                                              out_zq, counts, lossAcc);
    finalize<<<1, 256, 0, stream>>>(counts, lossAcc, out_loss, out_perp);
}

// Round 9
// 386.974 us; speedup vs baseline: 1.5986x; 1.5431x over previous
//
#include <hip/hip_runtime.h>
#include <stdint.h>
#include <math.h>

// Problem constants (fixed by reference file)
#define NROWS 32768     // B*S = 8*4096
#define DIM   256
#define KCODES 8192
#define BETA  0.25f
#define CSPLIT 4        // code splits across gemm_hi grid.y
#define RSPLIT 16       // rescue col-splits (512 cols each)
#define NELEM 8388608   // NROWS*DIM
// margin threshold: hi-only pair-error sigma ~4e-3; tau ~ 23 sigma. Rows with
// min2-min1 < tau (~11% measured) get exact 3-term rescore via rescue_gemm.
#define TAU 0.09375f

typedef float f32x4 __attribute__((ext_vector_type(4)));
typedef _Float16 v8h __attribute__((ext_vector_type(8)));
typedef unsigned short us4 __attribute__((ext_vector_type(4)));

// ---------- fp16 two-term split (Ootomo): x ~= hi + lo ----------
__device__ inline unsigned int split1(float x) {
    _Float16 hf = (_Float16)x;
    _Float16 lf = (_Float16)(x - (float)hf);
    unsigned int h = __builtin_bit_cast(unsigned short, hf);
    unsigned int l = __builtin_bit_cast(unsigned short, lf);
    return h | (l << 16);
}

__device__ inline void gload_lds16(const void* g, void* l) {
    __builtin_amdgcn_global_load_lds(
        (const __attribute__((address_space(1))) void*)g,
        (__attribute__((address_space(3))) void*)l,
        16, 0, 0);
}

// float -> order-preserving uint32 (for packed atomicMin)
__device__ inline unsigned int fkey(float f) {
    unsigned int b = __float_as_uint(f);
    return (b & 0x80000000u) ? ~b : (b | 0x80000000u);
}

// ---------- prep: z -> (z_hi, z_lo) fp16 ----------
__global__ void prep_z(const float* __restrict__ z,
                       unsigned short* __restrict__ zhi,
                       unsigned short* __restrict__ zlo) {
    int t = blockIdx.x * blockDim.x + threadIdx.x;
    float4 v = reinterpret_cast<const float4*>(z)[t];
    unsigned int p0 = split1(v.x);
    unsigned int p1 = split1(v.y);
    unsigned int p2 = split1(v.z);
    unsigned int p3 = split1(v.w);
    us4 h, l;
    h[0] = (unsigned short)p0; l[0] = (unsigned short)(p0 >> 16);
    h[1] = (unsigned short)p1; l[1] = (unsigned short)(p1 >> 16);
    h[2] = (unsigned short)p2; l[2] = (unsigned short)(p2 >> 16);
    h[3] = (unsigned short)p3; l[3] = (unsigned short)(p3 >> 16);
    reinterpret_cast<us4*>(zhi)[t] = h;
    reinterpret_cast<us4*>(zlo)[t] = l;
}

// ---------- prep: embed -> (e_hi, e_lo) fp16 + 0.5*||e||^2 fp32 ----------
__global__ void prep_e(const float* __restrict__ e,
                       unsigned short* __restrict__ ehi,
                       unsigned short* __restrict__ elo,
                       float* __restrict__ enrm) {
    int row = blockIdx.x;
    int d = threadIdx.x;
    float x = e[(size_t)row * DIM + d];
    unsigned int p = split1(x);
    ehi[(size_t)row * DIM + d] = (unsigned short)p;
    elo[(size_t)row * DIM + d] = (unsigned short)(p >> 16);
    float sq = x * x;
    #pragma unroll
    for (int off = 32; off; off >>= 1) sq += __shfl_down(sq, off);
    __shared__ float ps[4];
    if ((threadIdx.x & 63) == 0) ps[threadIdx.x >> 6] = sq;
    __syncthreads();
    if (threadIdx.x == 0) enrm[row] = 0.5f * (ps[0] + ps[1] + ps[2] + ps[3]);
}

// ---------- hi-only GEMM (K=256) + per-row (min1, argmin1, min2) ----------
// Structure = R4/R6 winner: BK=64, single-buffered 2-barrier K-loop, 0-conflict
// XOR swizzle. __launch_bounds__(256,2): without it the compiler allocated
// >256 regs/wave -> 1 block/CU -> MfmaUtil 17% (R7 post-mortem).
__launch_bounds__(256, 2)
__global__ void gemm_hi(const unsigned short* __restrict__ zhi,
                        const unsigned short* __restrict__ ehi,
                        const float* __restrict__ enrm,
                        float* __restrict__ pval1,
                        int* __restrict__ pcol1,
                        float* __restrict__ pval2) {
    __shared__ __align__(16) unsigned short As[128 * 64];   // 16 KB
    __shared__ __align__(16) unsigned short Bs[128 * 64];   // 16 KB
    __shared__ float rv[2][128];
    __shared__ int   rc[2][128];
    __shared__ float rv2[2][128];

    const int tid = threadIdx.x;
    const int w = tid >> 6, l = tid & 63;
    const int lx = l & 15, quad = l >> 4;
    const int wm = w >> 1, wn = w & 1;
    const int arow_base = blockIdx.x * 128;
    const int cs = blockIdx.y;
    const int cbase_cs = cs * (KCODES / CSPLIT);

    float runv[16], runv2[16];
    int runc[16];
    #pragma unroll
    for (int s = 0; s < 16; ++s) {
        runv[s] = 3.0e38f; runv2[s] = 3.0e38f; runc[s] = 0x7fffffff;
    }

    const int st_row8 = l >> 3;
    const int st_g = (((l & 7) ^ (l >> 3)) * 8);
    const int fr_lx7 = lx & 7;

    for (int nt = 0; nt < (KCODES / CSPLIT) / 128; ++nt) {   // 16 N-tiles
        const int colbase = cbase_cs + nt * 128;
        f32x4 acc[4][4];
        #pragma unroll
        for (int mi = 0; mi < 4; ++mi)
            #pragma unroll
            for (int ni = 0; ni < 4; ++ni) {
                f32x4 zz = {0.f, 0.f, 0.f, 0.f};
                acc[mi][ni] = zz;
            }

        for (int bk = 0; bk < 4; ++bk) {   // K=256, BK=64
            const int ao = bk * 64;
            __syncthreads();
            #pragma unroll
            for (int j = 0; j < 4; ++j) {
                const int r = w * 32 + j * 8 + st_row8;
                gload_lds16(zhi + (size_t)(arow_base + r) * DIM + ao + st_g,
                            &As[(w * 32 + j * 8) * 64]);
                gload_lds16(ehi + (size_t)(colbase + r) * DIM + ao + st_g,
                            &Bs[(w * 32 + j * 8) * 64]);
            }
            __syncthreads();

            #pragma unroll
            for (int kc = 0; kc < 2; ++kc) {
                const int gsw = ((kc * 4 + quad) ^ fr_lx7) * 8;
                v8h af[4], bfr[4];
                #pragma unroll
                for (int mi = 0; mi < 4; ++mi)
                    af[mi] = *(const v8h*)&As[(wm * 64 + mi * 16 + lx) * 64 + gsw];
                #pragma unroll
                for (int ni = 0; ni < 4; ++ni)
                    bfr[ni] = *(const v8h*)&Bs[(wn * 64 + ni * 16 + lx) * 64 + gsw];
                #pragma unroll
                for (int mi = 0; mi < 4; ++mi)
                    #pragma unroll
                    for (int ni = 0; ni < 4; ++ni)
                        acc[mi][ni] = __builtin_amdgcn_mfma_f32_16x16x32_f16(
                            af[mi], bfr[ni], acc[mi][ni], 0, 0, 0);
            }
        }

        // epilogue: 2-min update (tie -> margin 0 -> flagged -> rescue resolves)
        #pragma unroll
        for (int ni = 0; ni < 4; ++ni) {
            const int col = colbase + wn * 64 + ni * 16 + lx;
            const float es = enrm[col];
            #pragma unroll
            for (int mi = 0; mi < 4; ++mi)
                #pragma unroll
                for (int r = 0; r < 4; ++r) {
                    const int s = mi * 4 + r;
                    float sv = es - acc[mi][ni][r];
                    bool lt1 = sv < runv[s];
                    bool lt2 = sv < runv2[s];
                    float old1 = runv[s];
                    runv2[s] = lt1 ? old1 : (lt2 ? sv : runv2[s]);
                    runv[s] = lt1 ? sv : old1;
                    runc[s] = lt1 ? col : runc[s];
                }
        }
    }

    // cross-lane reduce over the 16 lx lanes (16 cols of same row per slot)
    #pragma unroll
    for (int s = 0; s < 16; ++s) {
        float v1 = runv[s], v2 = runv2[s];
        int c1 = runc[s];
        #pragma unroll
        for (int m = 1; m < 16; m <<= 1) {
            float ov1 = __shfl_xor(v1, m);
            int oc1 = __shfl_xor(c1, m);
            float ov2 = __shfl_xor(v2, m);
            float mx = fmaxf(v1, ov1);
            v2 = fminf(fminf(v2, ov2), mx);
            bool take = (ov1 < v1) || (ov1 == v1 && oc1 < c1);
            v1 = take ? ov1 : v1;
            c1 = take ? oc1 : c1;
        }
        if (lx == 0) {
            const int mi = s >> 2, r = s & 3;
            const int rl = wm * 64 + mi * 16 + quad * 4 + r;
            rv[wn][rl] = v1; rc[wn][rl] = c1; rv2[wn][rl] = v2;
        }
    }
    __syncthreads();
    if (tid < 128) {
        float v1 = rv[0][tid], v2 = rv2[0][tid];
        int c1 = rc[0][tid];
        float ov1 = rv[1][tid], ov2 = rv2[1][tid];
        int oc1 = rc[1][tid];
        float mx = fmaxf(v1, ov1);
        v2 = fminf(fminf(v2, ov2), mx);
        bool take = (ov1 < v1) || (ov1 == v1 && oc1 < c1);
        v1 = take ? ov1 : v1;
        c1 = take ? oc1 : c1;
        const size_t row = (size_t)arow_base + tid;
        pval1[row * CSPLIT + cs] = v1;
        pcol1[row * CSPLIT + cs] = c1;
        pval2[row * CSPLIT + cs] = v2;
    }
}

// ---------- merge splits, write tentative idx, flag low-margin rows ----------
__global__ void merge_flag(const float* __restrict__ pval1,
                           const int* __restrict__ pcol1,
                           const float* __restrict__ pval2,
                           int* __restrict__ colidx,
                           float* __restrict__ out_idx,
                           int* __restrict__ flagcnt,
                           int* __restrict__ flaglist) {
    int row = blockIdx.x * blockDim.x + threadIdx.x;
    float v1 = pval1[row * CSPLIT], v2 = pval2[row * CSPLIT];
    int c1 = pcol1[row * CSPLIT];
    #pragma unroll
    for (int cs = 1; cs < CSPLIT; ++cs) {
        float ov1 = pval1[row * CSPLIT + cs], ov2 = pval2[row * CSPLIT + cs];
        int oc1 = pcol1[row * CSPLIT + cs];
        float mx = fmaxf(v1, ov1);
        v2 = fminf(fminf(v2, ov2), mx);
        if (ov1 < v1 || (ov1 == v1 && oc1 < c1)) { v1 = ov1; c1 = oc1; }
    }
    colidx[row] = c1;
    out_idx[row] = (float)c1;
    if (v2 - v1 < TAU) {
        int slot = atomicAdd(flagcnt, 1);
        flaglist[slot] = row;   // cap 32768 = NROWS, cannot overflow
    }
}

// ---------- rescue: exact 3-term split GEMM over flagged rows ----------
// A' = [zhi|zhi|zlo], B' = [ehi|elo|ehi] (K=768) -- same arithmetic that scored
// absmax=0 full-problem (R2/R4/R6) and as rescue (R7). Grid (32, RSPLIT=16):
// 512-col splits give ~450 active blocks at count~3500 (R8's rescue_scan was
// latency-bound at 8% occupancy with uncoalesced reads -- 291 us).
// Cross-split merge via packed 64-bit atomicMin (sortable score | col).
__launch_bounds__(256, 2)
__global__ void rescue_gemm(const unsigned short* __restrict__ zhi,
                            const unsigned short* __restrict__ zlo,
                            const unsigned short* __restrict__ ehi,
                            const unsigned short* __restrict__ elo,
                            const float* __restrict__ enrm,
                            const int* __restrict__ flagcnt,
                            const int* __restrict__ flaglist,
                            unsigned long long* __restrict__ rkey) {
    __shared__ __align__(16) unsigned short As[128 * 64];
    __shared__ __align__(16) unsigned short Bs[128 * 64];
    __shared__ float rv[2][128];
    __shared__ int   rc[2][128];

    const int count = *flagcnt;
    const int tid = threadIdx.x;
    const int w = tid >> 6, l = tid & 63;
    const int lx = l & 15, quad = l >> 4;
    const int wm = w >> 1, wn = w & 1;
    const int cs = blockIdx.y;                       // 0..15
    const int cbase_cs = cs * (KCODES / RSPLIT);     // 512 cols per split

    const int st_row8 = l >> 3;
    const int st_g = (((l & 7) ^ (l >> 3)) * 8);
    const int fr_lx7 = lx & 7;

    for (int tb = blockIdx.x * 128; tb < count; tb += 32 * 128) {
        // per-lane A-source rows (indirect through flaglist; pad -> row 0,
        // writes are count-guarded)
        int arowj[4];
        #pragma unroll
        for (int j = 0; j < 4; ++j) {
            int li = tb + w * 32 + j * 8 + st_row8;
            arowj[j] = (li < count) ? flaglist[li] : 0;
        }

        float runv[16];
        int runc[16];
        #pragma unroll
        for (int s = 0; s < 16; ++s) { runv[s] = 3.0e38f; runc[s] = 0x7fffffff; }

        for (int nt = 0; nt < (KCODES / RSPLIT) / 128; ++nt) {   // 4 N-tiles
            const int colbase = cbase_cs + nt * 128;
            f32x4 acc[4][4];
            #pragma unroll
            for (int mi = 0; mi < 4; ++mi)
                #pragma unroll
                for (int ni = 0; ni < 4; ++ni) {
                    f32x4 zz = {0.f, 0.f, 0.f, 0.f};
                    acc[mi][ni] = zz;
                }

            #pragma unroll
            for (int seg = 0; seg < 3; ++seg) {
                const unsigned short* za = (seg == 2) ? zlo : zhi;
                const unsigned short* eb = (seg == 1) ? elo : ehi;
                for (int bk = 0; bk < 4; ++bk) {
                    const int ao = bk * 64;
                    __syncthreads();
                    #pragma unroll
                    for (int j = 0; j < 4; ++j) {
                        const int r = w * 32 + j * 8 + st_row8;
                        gload_lds16(za + (size_t)arowj[j] * DIM + ao + st_g,
                                    &As[(w * 32 + j * 8) * 64]);
                        gload_lds16(eb + (size_t)(colbase + r) * DIM + ao + st_g,
                                    &Bs[(w * 32 + j * 8) * 64]);
                    }
                    __syncthreads();
                    #pragma unroll
                    for (int kc = 0; kc < 2; ++kc) {
                        const int gsw = ((kc * 4 + quad) ^ fr_lx7) * 8;
                        v8h af[4], bfr[4];
                        #pragma unroll
                        for (int mi = 0; mi < 4; ++mi)
                            af[mi] = *(const v8h*)&As[(wm * 64 + mi * 16 + lx) * 64 + gsw];
                        #pragma unroll
                        for (int ni = 0; ni < 4; ++ni)
                            bfr[ni] = *(const v8h*)&Bs[(wn * 64 + ni * 16 + lx) * 64 + gsw];
                        #pragma unroll
                        for (int mi = 0; mi < 4; ++mi)
                            #pragma unroll
                            for (int ni = 0; ni < 4; ++ni)
                                acc[mi][ni] = __builtin_amdgcn_mfma_f32_16x16x32_f16(
                                    af[mi], bfr[ni], acc[mi][ni], 0, 0, 0);
                    }
                }
            }

            #pragma unroll
            for (int ni = 0; ni < 4; ++ni) {
                const int col = colbase + wn * 64 + ni * 16 + lx;
                const float es = enrm[col];
                #pragma unroll
                for (int mi = 0; mi < 4; ++mi)
                    #pragma unroll
                    for (int r = 0; r < 4; ++r) {
                        float sv = es - acc[mi][ni][r];
                        const int s = mi * 4 + r;
                        if (sv < runv[s]) { runv[s] = sv; runc[s] = col; }
                    }
            }
        }

        #pragma unroll
        for (int s = 0; s < 16; ++s) {
            float v = runv[s]; int c = runc[s];
            #pragma unroll
            for (int m = 1; m < 16; m <<= 1) {
                float ov = __shfl_xor(v, m);
                int oc = __shfl_xor(c, m);
                if (ov < v || (ov == v && oc < c)) { v = ov; c = oc; }
            }
            if (lx == 0) {
                const int mi = s >> 2, r = s & 3;
                const int rl = wm * 64 + mi * 16 + quad * 4 + r;
                rv[wn][rl] = v; rc[wn][rl] = c;
            }
        }
        __syncthreads();
        if (tid < 128) {
            float v0 = rv[0][tid]; int c0 = rc[0][tid];
            float v1 = rv[1][tid]; int c1 = rc[1][tid];
            if (v1 < v0 || (v1 == v0 && c1 < c0)) { v0 = v1; c0 = c1; }
            const int li = tb + tid;
            if (li < count) {
                unsigned long long key =
                    ((unsigned long long)fkey(v0) << 32) | (unsigned int)c0;
                atomicMin(&rkey[li], key);
            }
        }
        __syncthreads();
    }
}

// ---------- write back rescued argmins ----------
__global__ void rescue_write(const unsigned long long* __restrict__ rkey,
                             const int* __restrict__ flagcnt,
                             const int* __restrict__ flaglist,
                             int* __restrict__ colidx,
                             float* __restrict__ out_idx) {
    int i = blockIdx.x * blockDim.x + threadIdx.x;
    if (i >= *flagcnt) return;
    int row = flaglist[i];
    int col = (int)(unsigned int)(rkey[i] & 0xFFFFFFFFull);
    colidx[row] = col;
    out_idx[row] = (float)col;
}

// ---------- gather z_q, z_q_st, loss, histogram ----------
__global__ void fused_out(const int* __restrict__ colidx,
                          const float* __restrict__ z,
                          const float* __restrict__ embed,
                          float* __restrict__ out_zq,
                          float* __restrict__ counts,
                          float* __restrict__ lossAcc) {
    __shared__ int cidx[16];
    const int tid = threadIdx.x;
    if (tid < 16) {
        const int row = blockIdx.x * 16 + tid;
        const int c = colidx[row];
        cidx[tid] = c;
        atomicAdd(&counts[c], 1.0f);
    }
    __syncthreads();
    const int d = tid;
    float ls = 0.f;
    #pragma unroll 4
    for (int i = 0; i < 16; ++i) {
        const int row = blockIdx.x * 16 + i;
        const int c = cidx[i];
        const float zv = z[(size_t)row * DIM + d];
        const float ev = embed[(size_t)c * DIM + d];
        const float diff = ev - zv;
        out_zq[(size_t)row * DIM + d] = zv + diff;
        ls += diff * diff;
    }
    #pragma unroll
    for (int off = 32; off; off >>= 1) ls += __shfl_down(ls, off);
    __shared__ float ps[4];
    if ((tid & 63) == 0) ps[tid >> 6] = ls;
    __syncthreads();
    if (tid == 0) atomicAdd(lossAcc, ps[0] + ps[1] + ps[2] + ps[3]);
}

// ---------- loss scale + perplexity ----------
__global__ void finalize(const float* __restrict__ counts,
                         const float* __restrict__ lossAcc,
                         float* __restrict__ out_loss,
                         float* __restrict__ out_perp) {
    float h = 0.f;
    for (int k = threadIdx.x; k < KCODES; k += 256) {
        float p = counts[k] * (1.0f / (float)NROWS);
        h += p * logf(p + 1e-12f);
    }
    #pragma unroll
    for (int off = 32; off; off >>= 1) h += __shfl_down(h, off);
    __shared__ float ps[4];
    if ((threadIdx.x & 63) == 0) ps[threadIdx.x >> 6] = h;
    __syncthreads();
    if (threadIdx.x == 0) {
        *out_perp = expf(-(ps[0] + ps[1] + ps[2] + ps[3]));
        *out_loss = BETA * lossAcc[0] / (float)NELEM;
    }
}

extern "C" void kernel_launch(void* const* d_in, const int* in_sizes, int n_in,
                              void* d_out, int out_size, void* d_ws, size_t ws_size,
                              hipStream_t stream) {
    const float* z = (const float*)d_in[0];       // [32768, 256] f32
    const float* embed = (const float*)d_in[1];   // [8192, 256] f32
    char* ws = (char*)d_ws;

    // workspace layout (~44.1 MB)
    unsigned short* zhi = (unsigned short*)(ws + 0);           // 16 MB
    unsigned short* zlo = (unsigned short*)(ws + 16777216);    // 16 MB
    unsigned short* ehi = (unsigned short*)(ws + 33554432);    // 4 MB
    unsigned short* elo = (unsigned short*)(ws + 37748736);    // 4 MB
    float* enrm    = (float*)(ws + 41943040);                  // 32 KB
    float* pval1   = (float*)(ws + 41975808);                  // 512 KB
    int*   pcol1   = (int*)  (ws + 42500096);                  // 512 KB
    float* pval2   = (float*)(ws + 43024384);                  // 512 KB
    int*   colidx  = (int*)  (ws + 43548672);                  // 128 KB
    float* counts  = (float*)(ws + 43679744);                  // 32 KB
    float* lossAcc = (float*)(ws + 43712512);                  // 4 B
    int*   flagcnt = (int*)  (ws + 43712516);                  // 4 B
    int*   flaglist = (int*) (ws + 43712520);                  // 128 KB (8B-aligned end)
    unsigned long long* rkey = (unsigned long long*)(ws + 43843592); // 256 KB

    float* out = (float*)d_out;
    float* out_zq   = out;                 // 8388608
    float* out_loss = out + 8388608;       // 1
    float* out_perp = out + 8388609;       // 1
    float* out_idx  = out + 8388610;       // 32768 (indices as f32)

    // zero histogram + loss accumulator + flag counter; 0xFF-init rescue keys
    (void)hipMemsetAsync(counts, 0, KCODES * 4 + 8, stream);
    (void)hipMemsetAsync(rkey, 0xFF, NROWS * 8, stream);

    prep_z<<<NELEM / 4 / 256, 256, 0, stream>>>(z, zhi, zlo);
    prep_e<<<KCODES, 256, 0, stream>>>(embed, ehi, elo, enrm);
    gemm_hi<<<dim3(NROWS / 128, CSPLIT), 256, 0, stream>>>(
        zhi, ehi, enrm, pval1, pcol1, pval2);
    merge_flag<<<NROWS / 256, 256, 0, stream>>>(
        pval1, pcol1, pval2, colidx, out_idx, flagcnt, flaglist);
    rescue_gemm<<<dim3(32, RSPLIT), 256, 0, stream>>>(
        zhi, zlo, ehi, elo, enrm, flagcnt, flaglist, rkey);
    rescue_write<<<NROWS / 256, 256, 0, stream>>>(
        rkey, flagcnt, flaglist, colidx, out_idx);
    fused_out<<<NROWS / 16, 256, 0, stream>>>(colidx, z, embed,
                                              out_zq, counts, lossAcc);
    finalize<<<1, 256, 0, stream>>>(counts, lossAcc, out_loss, out_perp);
}

// Round 10
// 368.204 us; speedup vs baseline: 1.6801x; 1.0510x over previous
//
#include <hip/hip_runtime.h>
#include <stdint.h>
#include <math.h>

// Problem constants (fixed by reference file)
#define NROWS 32768     // B*S = 8*4096
#define DIM   256
#define KCODES 8192
#define BETA  0.25f
#define CSPLIT 4        // code splits across gemm_hi grid.y
#define RSPLIT 16       // rescue col-splits (512 cols each)
#define NELEM 8388608   // NROWS*DIM
// margin threshold: hi-only pair-error sigma ~5e-3; tau ~ 19 sigma. Rows with
// min2-min1 < tau (~1-2% by order-statistics of 8192 Gaussian scores) get an
// exact 3-term rescore via rescue_gemm.
#define TAU 0.09375f

typedef float f32x4 __attribute__((ext_vector_type(4)));
typedef _Float16 v8h __attribute__((ext_vector_type(8)));
typedef unsigned short us4 __attribute__((ext_vector_type(4)));

// ---------- fp16 two-term split (Ootomo): x ~= hi + lo ----------
__device__ inline unsigned int split1(float x) {
    _Float16 hf = (_Float16)x;
    _Float16 lf = (_Float16)(x - (float)hf);
    unsigned int h = __builtin_bit_cast(unsigned short, hf);
    unsigned int l = __builtin_bit_cast(unsigned short, lf);
    return h | (l << 16);
}

__device__ inline void gload_lds16(const void* g, void* l) {
    __builtin_amdgcn_global_load_lds(
        (const __attribute__((address_space(1))) void*)g,
        (__attribute__((address_space(3))) void*)l,
        16, 0, 0);
}

// float -> order-preserving uint32 (for packed atomicMin)
__device__ inline unsigned int fkey(float f) {
    unsigned int b = __float_as_uint(f);
    return (b & 0x80000000u) ? ~b : (b | 0x80000000u);
}

// ---------- fused prep: z-split, e-split, enrm, and zero counters ----------
// blocks [0,8192): z -> (zhi, zlo). blocks [8192,16384): embed row -> (ehi, elo,
// enrm) + zero counts[row]; block 8192 also zeroes lossAcc/flagcnt.
__global__ void prep_all(const float* __restrict__ z,
                         const float* __restrict__ e,
                         unsigned short* __restrict__ zhi,
                         unsigned short* __restrict__ zlo,
                         unsigned short* __restrict__ ehi,
                         unsigned short* __restrict__ elo,
                         float* __restrict__ enrm,
                         float* __restrict__ counts,
                         float* __restrict__ lossAcc,
                         int* __restrict__ flagcnt) {
    if (blockIdx.x < 8192) {
        int t = blockIdx.x * 256 + threadIdx.x;   // float4 index
        float4 v = reinterpret_cast<const float4*>(z)[t];
        unsigned int p0 = split1(v.x);
        unsigned int p1 = split1(v.y);
        unsigned int p2 = split1(v.z);
        unsigned int p3 = split1(v.w);
        us4 h, l;
        h[0] = (unsigned short)p0; l[0] = (unsigned short)(p0 >> 16);
        h[1] = (unsigned short)p1; l[1] = (unsigned short)(p1 >> 16);
        h[2] = (unsigned short)p2; l[2] = (unsigned short)(p2 >> 16);
        h[3] = (unsigned short)p3; l[3] = (unsigned short)(p3 >> 16);
        reinterpret_cast<us4*>(zhi)[t] = h;
        reinterpret_cast<us4*>(zlo)[t] = l;
    } else {
        int row = blockIdx.x - 8192;
        int d = threadIdx.x;
        float x = e[(size_t)row * DIM + d];
        unsigned int p = split1(x);
        ehi[(size_t)row * DIM + d] = (unsigned short)p;
        elo[(size_t)row * DIM + d] = (unsigned short)(p >> 16);
        float sq = x * x;
        #pragma unroll
        for (int off = 32; off; off >>= 1) sq += __shfl_down(sq, off);
        __shared__ float ps[4];
        if ((threadIdx.x & 63) == 0) ps[threadIdx.x >> 6] = sq;
        __syncthreads();
        if (threadIdx.x == 0) {
            enrm[row] = 0.5f * (ps[0] + ps[1] + ps[2] + ps[3]);
            counts[row] = 0.f;
            if (row == 0) { *lossAcc = 0.f; *flagcnt = 0; }
        }
    }
}

// ---------- hi-only GEMM (K=256) + per-row (min1, argmin1, min2) ----------
// Structure = R4/R6 winner: BK=64, single-buffered 2-barrier K-loop, 0-conflict
// XOR swizzle. __launch_bounds__(256,2): without it the compiler allocated
// >256 regs/wave -> 1 block/CU -> MfmaUtil 17% (R7 post-mortem).
// Epilogue: min2 via v_med3_f32 (med3(sv,min1,min2) IS the 2nd-min recurrence
// given min1<=min2) -> 5 VALU/update vs 7 (R9: VALUBusy 41% > MfmaUtil 32%).
__launch_bounds__(256, 2)
__global__ void gemm_hi(const unsigned short* __restrict__ zhi,
                        const unsigned short* __restrict__ ehi,
                        const float* __restrict__ enrm,
                        float* __restrict__ pval1,
                        int* __restrict__ pcol1,
                        float* __restrict__ pval2) {
    __shared__ __align__(16) unsigned short As[128 * 64];   // 16 KB
    __shared__ __align__(16) unsigned short Bs[128 * 64];   // 16 KB
    __shared__ float rv[2][128];
    __shared__ int   rc[2][128];
    __shared__ float rv2[2][128];

    const int tid = threadIdx.x;
    const int w = tid >> 6, l = tid & 63;
    const int lx = l & 15, quad = l >> 4;
    const int wm = w >> 1, wn = w & 1;
    const int arow_base = blockIdx.x * 128;
    const int cs = blockIdx.y;
    const int cbase_cs = cs * (KCODES / CSPLIT);

    float runv[16], runv2[16];
    int runc[16];
    #pragma unroll
    for (int s = 0; s < 16; ++s) {
        runv[s] = 3.0e38f; runv2[s] = 3.0e38f; runc[s] = 0x7fffffff;
    }

    const int st_row8 = l >> 3;
    const int st_g = (((l & 7) ^ (l >> 3)) * 8);
    const int fr_lx7 = lx & 7;

    for (int nt = 0; nt < (KCODES / CSPLIT) / 128; ++nt) {   // 16 N-tiles
        const int colbase = cbase_cs + nt * 128;
        f32x4 acc[4][4];
        #pragma unroll
        for (int mi = 0; mi < 4; ++mi)
            #pragma unroll
            for (int ni = 0; ni < 4; ++ni) {
                f32x4 zz = {0.f, 0.f, 0.f, 0.f};
                acc[mi][ni] = zz;
            }

        for (int bk = 0; bk < 4; ++bk) {   // K=256, BK=64
            const int ao = bk * 64;
            __syncthreads();
            #pragma unroll
            for (int j = 0; j < 4; ++j) {
                const int r = w * 32 + j * 8 + st_row8;
                gload_lds16(zhi + (size_t)(arow_base + r) * DIM + ao + st_g,
                            &As[(w * 32 + j * 8) * 64]);
                gload_lds16(ehi + (size_t)(colbase + r) * DIM + ao + st_g,
                            &Bs[(w * 32 + j * 8) * 64]);
            }
            __syncthreads();

            #pragma unroll
            for (int kc = 0; kc < 2; ++kc) {
                const int gsw = ((kc * 4 + quad) ^ fr_lx7) * 8;
                v8h af[4], bfr[4];
                #pragma unroll
                for (int mi = 0; mi < 4; ++mi)
                    af[mi] = *(const v8h*)&As[(wm * 64 + mi * 16 + lx) * 64 + gsw];
                #pragma unroll
                for (int ni = 0; ni < 4; ++ni)
                    bfr[ni] = *(const v8h*)&Bs[(wn * 64 + ni * 16 + lx) * 64 + gsw];
                #pragma unroll
                for (int mi = 0; mi < 4; ++mi)
                    #pragma unroll
                    for (int ni = 0; ni < 4; ++ni)
                        acc[mi][ni] = __builtin_amdgcn_mfma_f32_16x16x32_f16(
                            af[mi], bfr[ni], acc[mi][ni], 0, 0, 0);
            }
        }

        // epilogue: 2-min update, 5 VALU/update (sub, med3, cmp, cndmask, min).
        // tie -> margin 0 -> flagged -> rescue resolves exactly.
        #pragma unroll
        for (int ni = 0; ni < 4; ++ni) {
            const int col = colbase + wn * 64 + ni * 16 + lx;
            const float es = enrm[col];
            #pragma unroll
            for (int mi = 0; mi < 4; ++mi)
                #pragma unroll
                for (int r = 0; r < 4; ++r) {
                    const int s = mi * 4 + r;
                    float sv = es - acc[mi][ni][r];
                    bool lt = sv < runv[s];
                    runv2[s] = __builtin_amdgcn_fmed3f(sv, runv[s], runv2[s]);
                    runc[s] = lt ? col : runc[s];
                    runv[s] = fminf(runv[s], sv);
                }
        }
    }

    // cross-lane reduce over the 16 lx lanes (16 cols of same row per slot)
    #pragma unroll
    for (int s = 0; s < 16; ++s) {
        float v1 = runv[s], v2 = runv2[s];
        int c1 = runc[s];
        #pragma unroll
        for (int m = 1; m < 16; m <<= 1) {
            float ov1 = __shfl_xor(v1, m);
            int oc1 = __shfl_xor(c1, m);
            float ov2 = __shfl_xor(v2, m);
            float mx = fmaxf(v1, ov1);
            v2 = fminf(fminf(v2, ov2), mx);
            bool take = (ov1 < v1) || (ov1 == v1 && oc1 < c1);
            v1 = take ? ov1 : v1;
            c1 = take ? oc1 : c1;
        }
        if (lx == 0) {
            const int mi = s >> 2, r = s & 3;
            const int rl = wm * 64 + mi * 16 + quad * 4 + r;
            rv[wn][rl] = v1; rc[wn][rl] = c1; rv2[wn][rl] = v2;
        }
    }
    __syncthreads();
    if (tid < 128) {
        float v1 = rv[0][tid], v2 = rv2[0][tid];
        int c1 = rc[0][tid];
        float ov1 = rv[1][tid], ov2 = rv2[1][tid];
        int oc1 = rc[1][tid];
        float mx = fmaxf(v1, ov1);
        v2 = fminf(fminf(v2, ov2), mx);
        bool take = (ov1 < v1) || (ov1 == v1 && oc1 < c1);
        v1 = take ? ov1 : v1;
        c1 = take ? oc1 : c1;
        const size_t row = (size_t)arow_base + tid;
        pval1[row * CSPLIT + cs] = v1;
        pcol1[row * CSPLIT + cs] = c1;
        pval2[row * CSPLIT + cs] = v2;
    }
}

// ---------- merge splits; tentative idx; flag low-margin rows ----------
// Flagged rows: colidx = -(slot+1) sentinel, rkey[slot] pre-set to ~0 for the
// rescue atomicMin merge. fused_out decodes (kills the rescue_write dispatch).
__global__ void merge_flag(const float* __restrict__ pval1,
                           const int* __restrict__ pcol1,
                           const float* __restrict__ pval2,
                           int* __restrict__ colidx,
                           float* __restrict__ out_idx,
                           int* __restrict__ flagcnt,
                           int* __restrict__ flaglist,
                           unsigned long long* __restrict__ rkey) {
    int row = blockIdx.x * blockDim.x + threadIdx.x;
    float v1 = pval1[row * CSPLIT], v2 = pval2[row * CSPLIT];
    int c1 = pcol1[row * CSPLIT];
    #pragma unroll
    for (int cs = 1; cs < CSPLIT; ++cs) {
        float ov1 = pval1[row * CSPLIT + cs], ov2 = pval2[row * CSPLIT + cs];
        int oc1 = pcol1[row * CSPLIT + cs];
        float mx = fmaxf(v1, ov1);
        v2 = fminf(fminf(v2, ov2), mx);
        if (ov1 < v1 || (ov1 == v1 && oc1 < c1)) { v1 = ov1; c1 = oc1; }
    }
    out_idx[row] = (float)c1;
    if (v2 - v1 < TAU) {
        int slot = atomicAdd(flagcnt, 1);
        flaglist[slot] = row;           // cap 32768 = NROWS, cannot overflow
        rkey[slot] = ~0ull;
        colidx[row] = -(slot + 1);      // sentinel: decode in fused_out
    } else {
        colidx[row] = c1;
    }
}

// ---------- rescue: exact 3-term split GEMM over flagged rows ----------
// A' = [zhi|zhi|zlo], B' = [ehi|elo|ehi] (K=768) -- the arithmetic that scored
// absmax=0 full-problem (R2/R4/R6). Grid (32, RSPLIT); idle blocks exit fast.
// Cross-split merge via packed 64-bit atomicMin (sortable score | col).
__launch_bounds__(256, 2)
__global__ void rescue_gemm(const unsigned short* __restrict__ zhi,
                            const unsigned short* __restrict__ zlo,
                            const unsigned short* __restrict__ ehi,
                            const unsigned short* __restrict__ elo,
                            const float* __restrict__ enrm,
                            const int* __restrict__ flagcnt,
                            const int* __restrict__ flaglist,
                            unsigned long long* __restrict__ rkey) {
    __shared__ __align__(16) unsigned short As[128 * 64];
    __shared__ __align__(16) unsigned short Bs[128 * 64];
    __shared__ float rv[2][128];
    __shared__ int   rc[2][128];

    const int count = *flagcnt;
    const int tid = threadIdx.x;
    const int w = tid >> 6, l = tid & 63;
    const int lx = l & 15, quad = l >> 4;
    const int wm = w >> 1, wn = w & 1;
    const int cs = blockIdx.y;                       // 0..RSPLIT-1
    const int cbase_cs = cs * (KCODES / RSPLIT);     // 512 cols per split

    const int st_row8 = l >> 3;
    const int st_g = (((l & 7) ^ (l >> 3)) * 8);
    const int fr_lx7 = lx & 7;

    for (int tb = blockIdx.x * 128; tb < count; tb += 32 * 128) {
        int arowj[4];
        #pragma unroll
        for (int j = 0; j < 4; ++j) {
            int li = tb + w * 32 + j * 8 + st_row8;
            arowj[j] = (li < count) ? flaglist[li] : 0;
        }

        float runv[16];
        int runc[16];
        #pragma unroll
        for (int s = 0; s < 16; ++s) { runv[s] = 3.0e38f; runc[s] = 0x7fffffff; }

        for (int nt = 0; nt < (KCODES / RSPLIT) / 128; ++nt) {   // 4 N-tiles
            const int colbase = cbase_cs + nt * 128;
            f32x4 acc[4][4];
            #pragma unroll
            for (int mi = 0; mi < 4; ++mi)
                #pragma unroll
                for (int ni = 0; ni < 4; ++ni) {
                    f32x4 zz = {0.f, 0.f, 0.f, 0.f};
                    acc[mi][ni] = zz;
                }

            #pragma unroll
            for (int seg = 0; seg < 3; ++seg) {
                const unsigned short* za = (seg == 2) ? zlo : zhi;
                const unsigned short* eb = (seg == 1) ? elo : ehi;
                for (int bk = 0; bk < 4; ++bk) {
                    const int ao = bk * 64;
                    __syncthreads();
                    #pragma unroll
                    for (int j = 0; j < 4; ++j) {
                        const int r = w * 32 + j * 8 + st_row8;
                        gload_lds16(za + (size_t)arowj[j] * DIM + ao + st_g,
                                    &As[(w * 32 + j * 8) * 64]);
                        gload_lds16(eb + (size_t)(colbase + r) * DIM + ao + st_g,
                                    &Bs[(w * 32 + j * 8) * 64]);
                    }
                    __syncthreads();
                    #pragma unroll
                    for (int kc = 0; kc < 2; ++kc) {
                        const int gsw = ((kc * 4 + quad) ^ fr_lx7) * 8;
                        v8h af[4], bfr[4];
                        #pragma unroll
                        for (int mi = 0; mi < 4; ++mi)
                            af[mi] = *(const v8h*)&As[(wm * 64 + mi * 16 + lx) * 64 + gsw];
                        #pragma unroll
                        for (int ni = 0; ni < 4; ++ni)
                            bfr[ni] = *(const v8h*)&Bs[(wn * 64 + ni * 16 + lx) * 64 + gsw];
                        #pragma unroll
                        for (int mi = 0; mi < 4; ++mi)
                            #pragma unroll
                            for (int ni = 0; ni < 4; ++ni)
                                acc[mi][ni] = __builtin_amdgcn_mfma_f32_16x16x32_f16(
                                    af[mi], bfr[ni], acc[mi][ni], 0, 0, 0);
                    }
                }
            }

            #pragma unroll
            for (int ni = 0; ni < 4; ++ni) {
                const int col = colbase + wn * 64 + ni * 16 + lx;
                const float es = enrm[col];
                #pragma unroll
                for (int mi = 0; mi < 4; ++mi)
                    #pragma unroll
                    for (int r = 0; r < 4; ++r) {
                        float sv = es - acc[mi][ni][r];
                        const int s = mi * 4 + r;
                        if (sv < runv[s]) { runv[s] = sv; runc[s] = col; }
                    }
            }
        }

        #pragma unroll
        for (int s = 0; s < 16; ++s) {
            float v = runv[s]; int c = runc[s];
            #pragma unroll
            for (int m = 1; m < 16; m <<= 1) {
                float ov = __shfl_xor(v, m);
                int oc = __shfl_xor(c, m);
                if (ov < v || (ov == v && oc < c)) { v = ov; c = oc; }
            }
            if (lx == 0) {
                const int mi = s >> 2, r = s & 3;
                const int rl = wm * 64 + mi * 16 + quad * 4 + r;
                rv[wn][rl] = v; rc[wn][rl] = c;
            }
        }
        __syncthreads();
        if (tid < 128) {
            float v0 = rv[0][tid]; int c0 = rc[0][tid];
            float v1 = rv[1][tid]; int c1 = rc[1][tid];
            if (v1 < v0 || (v1 == v0 && c1 < c0)) { v0 = v1; c0 = c1; }
            const int li = tb + tid;
            if (li < count) {
                unsigned long long key =
                    ((unsigned long long)fkey(v0) << 32) | (unsigned int)c0;
                atomicMin(&rkey[li], key);
            }
        }
        __syncthreads();
    }
}

// ---------- gather z_q, z_q_st, loss, histogram; decode rescued rows ----------
__global__ void fused_out(const int* __restrict__ colidx,
                          const unsigned long long* __restrict__ rkey,
                          const float* __restrict__ z,
                          const float* __restrict__ embed,
                          float* __restrict__ out_zq,
                          float* __restrict__ out_idx,
                          float* __restrict__ counts,
                          float* __restrict__ lossAcc) {
    __shared__ int cidx[16];
    const int tid = threadIdx.x;
    if (tid < 16) {
        const int row = blockIdx.x * 16 + tid;
        int c = colidx[row];
        if (c < 0) {                      // rescued row: decode packed key
            c = (int)(unsigned int)(rkey[-c - 1] & 0x1FFFull);
            out_idx[row] = (float)c;
        }
        cidx[tid] = c;
        atomicAdd(&counts[c], 1.0f);
    }
    __syncthreads();
    const int d = tid;
    float ls = 0.f;
    #pragma unroll 4
    for (int i = 0; i < 16; ++i) {
        const int row = blockIdx.x * 16 + i;
        const int c = cidx[i];
        const float zv = z[(size_t)row * DIM + d];
        const float ev = embed[(size_t)c * DIM + d];
        const float diff = ev - zv;
        out_zq[(size_t)row * DIM + d] = zv + diff;
        ls += diff * diff;
    }
    #pragma unroll
    for (int off = 32; off; off >>= 1) ls += __shfl_down(ls, off);
    __shared__ float ps[4];
    if ((tid & 63) == 0) ps[tid >> 6] = ls;
    __syncthreads();
    if (tid == 0) atomicAdd(lossAcc, ps[0] + ps[1] + ps[2] + ps[3]);
}

// ---------- loss scale + perplexity ----------
__global__ void finalize(const float* __restrict__ counts,
                         const float* __restrict__ lossAcc,
                         float* __restrict__ out_loss,
                         float* __restrict__ out_perp) {
    float h = 0.f;
    for (int k = threadIdx.x; k < KCODES; k += 256) {
        float p = counts[k] * (1.0f / (float)NROWS);
        h += p * logf(p + 1e-12f);
    }
    #pragma unroll
    for (int off = 32; off; off >>= 1) h += __shfl_down(h, off);
    __shared__ float ps[4];
    if ((threadIdx.x & 63) == 0) ps[threadIdx.x >> 6] = h;
    __syncthreads();
    if (threadIdx.x == 0) {
        *out_perp = expf(-(ps[0] + ps[1] + ps[2] + ps[3]));
        *out_loss = BETA * lossAcc[0] / (float)NELEM;
    }
}

extern "C" void kernel_launch(void* const* d_in, const int* in_sizes, int n_in,
                              void* d_out, int out_size, void* d_ws, size_t ws_size,
                              hipStream_t stream) {
    const float* z = (const float*)d_in[0];       // [32768, 256] f32
    const float* embed = (const float*)d_in[1];   // [8192, 256] f32
    char* ws = (char*)d_ws;

    // workspace layout (~44.1 MB)
    unsigned short* zhi = (unsigned short*)(ws + 0);           // 16 MB
    unsigned short* zlo = (unsigned short*)(ws + 16777216);    // 16 MB
    unsigned short* ehi = (unsigned short*)(ws + 33554432);    // 4 MB
    unsigned short* elo = (unsigned short*)(ws + 37748736);    // 4 MB
    float* enrm    = (float*)(ws + 41943040);                  // 32 KB
    float* pval1   = (float*)(ws + 41975808);                  // 512 KB
    int*   pcol1   = (int*)  (ws + 42500096);                  // 512 KB
    float* pval2   = (float*)(ws + 43024384);                  // 512 KB
    int*   colidx  = (int*)  (ws + 43548672);                  // 128 KB
    float* counts  = (float*)(ws + 43679744);                  // 32 KB
    float* lossAcc = (float*)(ws + 43712512);                  // 4 B
    int*   flagcnt = (int*)  (ws + 43712516);                  // 4 B
    int*   flaglist = (int*) (ws + 43712520);                  // 128 KB (8B-aligned end)
    unsigned long long* rkey = (unsigned long long*)(ws + 43843592); // 256 KB

    float* out = (float*)d_out;
    float* out_zq   = out;                 // 8388608
    float* out_loss = out + 8388608;       // 1
    float* out_perp = out + 8388609;       // 1
    float* out_idx  = out + 8388610;       // 32768 (indices as f32)

    // 6 dispatches total (R9 had 10; ~10us/dispatch gap overhead measured)
    prep_all<<<16384, 256, 0, stream>>>(z, embed, zhi, zlo, ehi, elo, enrm,
                                        counts, lossAcc, flagcnt);
    gemm_hi<<<dim3(NROWS / 128, CSPLIT), 256, 0, stream>>>(
        zhi, ehi, enrm, pval1, pcol1, pval2);
    merge_flag<<<NROWS / 256, 256, 0, stream>>>(
        pval1, pcol1, pval2, colidx, out_idx, flagcnt, flaglist, rkey);
    rescue_gemm<<<dim3(32, RSPLIT), 256, 0, stream>>>(
        zhi, zlo, ehi, elo, enrm, flagcnt, flaglist, rkey);
    fused_out<<<NROWS / 16, 256, 0, stream>>>(colidx, rkey, z, embed,
                                              out_zq, out_idx, counts, lossAcc);
    finalize<<<1, 256, 0, stream>>>(counts, lossAcc, out_loss, out_perp);
}